// Round 11
// baseline (57.816 us; speedup 1.0000x reference)
//
#include <hip/hip_runtime.h>

// B=64, H=W=512, K=7, VALID conv -> 506x506.
// v10b: LDS-free direct conv, 4-col x 4-row register micro-tile.
// v9 post-mortem: 4x8 tile -> 116 VGPR -> 4 waves/SIMD -> 72% issue stall.
// Halve live state (acc16 + f10 ~ 30 floats) so natural alloc ~64-80 VGPR
// gives 6-7 waves/SIMD. No __launch_bounds__ cap (v3/v4/v7 spill disasters).
// Non-temporal stores keep the write-once output from evicting re-read
// input rows out of L2. (v10 compile fix: the builtin needs a NATIVE vector
// type, not HIP's float2 class -> use ext_vector_type(2).)
#define HW 512
#define OW 506

typedef float vfloat2 __attribute__((ext_vector_type(2)));

__global__ __launch_bounds__(256) void conv7x7_v10(
    const float* __restrict__ in,      // [64][512][512]
    const float* __restrict__ weight,  // [7][7]
    const float* __restrict__ bias,    // [1]
    float* __restrict__ out)           // [64][506][506]
{
    const int tid  = threadIdx.x;
    const int lane = tid & 63;
    const int w    = tid >> 6;
    const int x0   = blockIdx.x * 256;          // 64 lanes x 4 cols
    const int yb   = blockIdx.y * 16 + w * 4;   // wave's first output row
    const int b    = blockIdx.z;

    // ---- weights + bias -> SGPRs (uniform, statically indexed) ----
    float wv[49];
#pragma unroll
    for (int i = 0; i < 49; ++i)
        wv[i] = __uint_as_float(__builtin_amdgcn_readfirstlane(__float_as_uint(weight[i])));
    const float bv = __uint_as_float(__builtin_amdgcn_readfirstlane(__float_as_uint(bias[0])));

    const float* __restrict__ ib = in + (size_t)b * (HW * HW);

    // Output cols cb..cb+3. Clamped load bases stay in-row; clamped lanes'
    // garbage only feeds outputs that the store guards reject:
    //  - cbl<cb only when cb=508 (all 4 outputs >=506)
    //  - c2b<cb+8 only when cb>=504 (f10[8..9] feed outputs cb+2,cb+3 >=506)
    const int cb  = x0 + 4 * lane;
    const int cbl = min(cb, HW - 8);        // 16B-aligned float4-pair base
    const int c2b = min(cb + 8, HW - 2);    // 8B-aligned float2 base

    float acc[16];
#pragma unroll
    for (int i = 0; i < 16; ++i) acc[i] = 0.f;

    // 10 input rows feed 4 output rows x 4 cols.
#pragma unroll
    for (int ir = 0; ir < 10; ++ir) {
        const int row = min(yb + ir, HW - 1);      // wave-uniform clamp
        const float* p = ib + row * HW;
        const float4 q0 = *reinterpret_cast<const float4*>(p + cbl);
        const float4 q1 = *reinterpret_cast<const float4*>(p + cbl + 4);
        const float2 c2 = *reinterpret_cast<const float2*>(p + c2b);
        const float f10[10] = {q0.x, q0.y, q0.z, q0.w,
                               q1.x, q1.y, q1.z, q1.w,
                               c2.x, c2.y};

#pragma unroll
        for (int kr = 0; kr < 7; ++kr) {
            const int s = ir - kr;                 // compile-time after unroll
            if (s >= 0 && s < 4) {
#pragma unroll
                for (int kc = 0; kc < 7; ++kc) {
                    const float wk = wv[kr * 7 + kc];
#pragma unroll
                    for (int j = 0; j < 4; ++j)
                        acc[s * 4 + j] = fmaf(wk, f10[kc + j], acc[s * 4 + j]);
                }
            }
        }
    }

    // ---- store: 4 cols as two native-vector float2, non-temporal ----
    float* __restrict__ outb = out + (size_t)b * (OW * OW);
#pragma unroll
    for (int s = 0; s < 4; ++s) {
        const int oy = yb + s;
        if (oy < OW) {
            float* orow = outb + (size_t)oy * OW + cb;
            if (cb + 1 < OW) {
                vfloat2 v0; v0.x = acc[s * 4 + 0] + bv; v0.y = acc[s * 4 + 1] + bv;
                __builtin_nontemporal_store(v0, reinterpret_cast<vfloat2*>(orow));
            }
            if (cb + 3 < OW) {
                vfloat2 v1; v1.x = acc[s * 4 + 2] + bv; v1.y = acc[s * 4 + 3] + bv;
                __builtin_nontemporal_store(v1, reinterpret_cast<vfloat2*>(orow + 2));
            }
        }
    }
}

extern "C" void kernel_launch(void* const* d_in, const int* in_sizes, int n_in,
                              void* d_out, int out_size, void* d_ws, size_t ws_size,
                              hipStream_t stream) {
    const float* enc_x  = (const float*)d_in[0];
    const float* weight = (const float*)d_in[1];
    const float* bias   = (const float*)d_in[2];
    float* outp         = (float*)d_out;

    // 2 x 256 cols, 32 x 16 rows (covers 506), 64 images = 4096 blocks.
    dim3 grid(2, 32, 64);
    dim3 block(256);
    hipLaunchKernelGGL(conv7x7_v10, grid, block, 0, stream,
                       enc_x, weight, bias, outp);
}

// Round 12
// 40.017 us; speedup vs baseline: 1.4448x; 1.4448x over previous
//
#include <hip/hip_runtime.h>

// B=64, H=W=512, K=7, VALID conv -> 506x506.
// v11 = v8's proven scalar-load engine + 4-col tap reuse, zero guards.
//  - v8 (60 VGPR, 8 waves/SIMD) pipelined 98 scalar loads/thread nearly
//    perfectly; v9/v10's float4 bundles stalled ~5x worse per instr.
//  - 4 cols x 4 rows/thread: 10 scalar loads/row, 2.5 loads/output.
//  - Shifted-overlap tiling (x0 in {0,250}; y0=min(16*by,490)) -> every
//    load in-bounds, every store valid: no clamps, no guards; overlap
//    regions written twice with identical values (deterministic).
//  - Plain stores (v10's non-temporal 8B stores doubled WRITE_SIZE).
//  - No __launch_bounds__ 2nd arg (v3/v4/v7 spill disasters).
#define HW 512
#define OW 506

__global__ __launch_bounds__(256) void conv7x7_v11(
    const float* __restrict__ in,      // [64][512][512]
    const float* __restrict__ weight,  // [7][7]
    const float* __restrict__ bias,    // [1]
    float* __restrict__ out)           // [64][506][506]
{
    const int tid  = threadIdx.x;
    const int lane = tid & 63;
    const int w    = tid >> 6;
    // x tiles: block 0 -> cols 0..255, block 1 -> cols 250..505 (overlap ok)
    const int x0   = blockIdx.x * 250;
    // y tiles: 16 rows/block, last block shifted so rows+halo stay in [0,512)
    const int y0   = min((int)blockIdx.y * 16, OW - 16);
    const int yb   = y0 + w * 4;                // wave's first output row
    const int b    = blockIdx.z;

    // ---- weights + bias -> SGPRs (uniform, statically indexed) ----
    float wv[49];
#pragma unroll
    for (int i = 0; i < 49; ++i)
        wv[i] = __uint_as_float(__builtin_amdgcn_readfirstlane(__float_as_uint(weight[i])));
    const float bv = __uint_as_float(__builtin_amdgcn_readfirstlane(__float_as_uint(bias[0])));

    const float* __restrict__ ib = in + (size_t)b * (HW * HW);

    const int cb = x0 + 4 * lane;               // first output col (<= 502)

    float acc[16];
#pragma unroll
    for (int i = 0; i < 16; ++i) acc[i] = 0.f;

    // 10 input rows feed 4 output rows x 4 cols. All loads in-bounds:
    // rows yb..yb+9 <= 511, cols cb..cb+9 <= 511.
    const float* p0 = ib + (size_t)yb * HW + cb;
#pragma unroll
    for (int ir = 0; ir < 10; ++ir) {
        const float* p = p0 + ir * HW;
        float win[10];
#pragma unroll
        for (int t = 0; t < 10; ++t) win[t] = p[t];   // scalar dword loads

#pragma unroll
        for (int kr = 0; kr < 7; ++kr) {
            const int s = ir - kr;                    // compile-time after unroll
            if (s >= 0 && s < 4) {
#pragma unroll
                for (int kc = 0; kc < 7; ++kc) {
                    const float wk = wv[kr * 7 + kc];
#pragma unroll
                    for (int j = 0; j < 4; ++j)
                        acc[s * 4 + j] = fmaf(wk, win[kc + j], acc[s * 4 + j]);
                }
            }
        }
    }

    // ---- store: 4 rows x 4 cols, two float2 per row, unguarded ----
    float* __restrict__ outb = out + (size_t)b * (OW * OW);
#pragma unroll
    for (int s = 0; s < 4; ++s) {
        float* orow = outb + (size_t)(yb + s) * OW + cb;  // cb even -> 8B aligned
        *reinterpret_cast<float2*>(orow) =
            make_float2(acc[s * 4 + 0] + bv, acc[s * 4 + 1] + bv);
        *reinterpret_cast<float2*>(orow + 2) =
            make_float2(acc[s * 4 + 2] + bv, acc[s * 4 + 3] + bv);
    }
}

extern "C" void kernel_launch(void* const* d_in, const int* in_sizes, int n_in,
                              void* d_out, int out_size, void* d_ws, size_t ws_size,
                              hipStream_t stream) {
    const float* enc_x  = (const float*)d_in[0];
    const float* weight = (const float*)d_in[1];
    const float* bias   = (const float*)d_in[2];
    float* outp         = (float*)d_out;

    // x: 2 tiles (0,250); y: 32 tiles of 16 rows (last shifted); z: 64 images.
    dim3 grid(2, 32, 64);
    dim3 block(256);
    hipLaunchKernelGGL(conv7x7_v11, grid, block, 0, stream,
                       enc_x, weight, bias, outp);
}

// Round 13
// 38.889 us; speedup vs baseline: 1.4867x; 1.0290x over previous
//
#include <hip/hip_runtime.h>

// B=64, H=W=512, K=7, VALID conv -> 506x506.
// v12 = guard-free shifted tiling (v11) + fully-used float4 loads (v9)
//       + block-uniform alignment-shift template (no per-lane selects).
// Model from R0-R11 counters: dur ~ max(VALU, L1-line-cycles, HBM, latency).
//   v8 : VALU 22, L1 25  -> 40us      v11: VALU 11, L1 45 -> 40us
//   v12: VALU 11, L1 ~13, HBM ~19 -> target 26-32us.
// Each wave float4-load spans 16 fully-used lines (vs v11's 16 sparse lines
// per 4B-load): 3 loads/row instead of 10, line-cycles/output 1.66 -> 0.47.
// No __launch_bounds__ cap (v3/v4/v7 spill disasters). Plain stores
// (v10's NT 8B stores doubled WRITE_SIZE).
#define HW 512
#define OW 506

// SH = block-uniform window shift: x-tile base 250 makes cb == 2 (mod 4);
// loading from the aligned base cb-SH and indexing f12[SH+...] keeps all
// float4s 16B-aligned with zero per-lane correction.
template<int SH>
__device__ __forceinline__ void conv_rows(const float* __restrict__ p0,
                                          const float (&wv)[49],
                                          float (&acc)[16]) {
#pragma unroll
    for (int ir = 0; ir < 10; ++ir) {
        const float* p = p0 + ir * HW;           // aligned, in-bounds by tiling
        const float4 q0 = *reinterpret_cast<const float4*>(p);
        const float4 q1 = *reinterpret_cast<const float4*>(p + 4);
        const float4 q2 = *reinterpret_cast<const float4*>(p + 8);
        const float f12[12] = {q0.x, q0.y, q0.z, q0.w,
                               q1.x, q1.y, q1.z, q1.w,
                               q2.x, q2.y, q2.z, q2.w};
#pragma unroll
        for (int kr = 0; kr < 7; ++kr) {
            const int s = ir - kr;               // compile-time after unroll
            if (s >= 0 && s < 4) {
#pragma unroll
                for (int kc = 0; kc < 7; ++kc) {
                    const float wk = wv[kr * 7 + kc];
#pragma unroll
                    for (int j = 0; j < 4; ++j)
                        acc[s * 4 + j] = fmaf(wk, f12[SH + kc + j], acc[s * 4 + j]);
                }
            }
        }
    }
}

__global__ __launch_bounds__(256) void conv7x7_v12(
    const float* __restrict__ in,      // [64][512][512]
    const float* __restrict__ weight,  // [7][7]
    const float* __restrict__ bias,    // [1]
    float* __restrict__ out)           // [64][506][506]
{
    const int tid  = threadIdx.x;
    const int lane = tid & 63;
    const int w    = tid >> 6;
    const int bx   = blockIdx.x;                // 0 or 1
    const int x0   = bx ? 250 : 0;              // tiles cover 0..255, 250..505
    const int y0   = min((int)blockIdx.y * 16, OW - 16);  // shifted last tile
    const int yb   = y0 + w * 4;                // wave's first output row (<=502)
    const int b    = blockIdx.z;

    // ---- weights + bias -> SGPRs (uniform, statically indexed) ----
    float wv[49];
#pragma unroll
    for (int i = 0; i < 49; ++i)
        wv[i] = __uint_as_float(__builtin_amdgcn_readfirstlane(__float_as_uint(weight[i])));
    const float bv = __uint_as_float(__builtin_amdgcn_readfirstlane(__float_as_uint(bias[0])));

    const float* __restrict__ ib = in + (size_t)b * (HW * HW);

    const int cb = x0 + 4 * lane;               // first output col
    // Aligned load base: bx=0 -> cb (==0 mod 4), window [cb..cb+11] <= 263.
    //                    bx=1 -> cb-2 (==0 mod 4), window [cb-2..cb+9] <= 511.
    const float* p0 = ib + (size_t)yb * HW + (cb - (bx ? 2 : 0));

    float acc[16];
#pragma unroll
    for (int i = 0; i < 16; ++i) acc[i] = 0.f;

    if (bx == 0) conv_rows<0>(p0, wv, acc);     // uniform SGPR branch
    else         conv_rows<2>(p0, wv, acc);

    // ---- store: 4 rows x 4 cols, two float2 per row, unguarded ----
    // (all outputs valid by construction: cb<=502 -> cols<=505; yb+3<=505)
    float* __restrict__ outb = out + (size_t)b * (OW * OW);
#pragma unroll
    for (int s = 0; s < 4; ++s) {
        float* orow = outb + (size_t)(yb + s) * OW + cb;   // cb even -> 8B aligned
        *reinterpret_cast<float2*>(orow) =
            make_float2(acc[s * 4 + 0] + bv, acc[s * 4 + 1] + bv);
        *reinterpret_cast<float2*>(orow + 2) =
            make_float2(acc[s * 4 + 2] + bv, acc[s * 4 + 3] + bv);
    }
}

extern "C" void kernel_launch(void* const* d_in, const int* in_sizes, int n_in,
                              void* d_out, int out_size, void* d_ws, size_t ws_size,
                              hipStream_t stream) {
    const float* enc_x  = (const float*)d_in[0];
    const float* weight = (const float*)d_in[1];
    const float* bias   = (const float*)d_in[2];
    float* outp         = (float*)d_out;

    // x: 2 overlapping 256-col tiles; y: 32 tiles of 16 rows (last shifted);
    // z: 64 images. 4096 blocks.
    dim3 grid(2, 32, 64);
    dim3 block(256);
    hipLaunchKernelGGL(conv7x7_v12, grid, block, 0, stream,
                       enc_x, weight, bias, outp);
}